// Round 1
// baseline (2128.208 us; speedup 1.0000x reference)
//
#include <hip/hip_runtime.h>
#include <math.h>

#define NG 4
#define NN 50000
#define NE 800000
#define DD 64

// ---- int32 vs int64 edge-index detection ----------------------------------
// Reference dtype is int64; harness doc says integers arrive as int32.
// Detect at runtime: if the buffer is little-endian int64 with values < 2^31,
// every odd 32-bit word is 0. With genuine int32 random indices in [0,50000),
// 128 consecutive odd words all being zero is impossible (~(1/50000)^128).
__global__ void detect_kernel(const int* __restrict__ ei, int* __restrict__ flag) {
    if (blockIdx.x == 0 && threadIdx.x == 0) {
        int any_nonzero = 0;
        for (int i = 0; i < 128; ++i) any_nonzero |= ei[2 * i + 1];
        flag[0] = (any_nonzero == 0) ? 1 : 0;  // 1 => int64
    }
}

__device__ __forceinline__ int load_idx(const int* __restrict__ ei, long pos, int is64) {
    return is64 ? ei[2 * pos] : ei[pos];
}

// ---- degree (shared by both layers) ----------------------------------------
__global__ void deg_kernel(const int* __restrict__ ei, const int* __restrict__ flag,
                           float* __restrict__ deg) {
    int is64 = flag[0];
    long total = (long)NG * NE;
    long stride = (long)gridDim.x * blockDim.x;
    for (long i = (long)blockIdx.x * blockDim.x + threadIdx.x; i < total; i += stride) {
        int g = (int)(i / NE);
        int e = (int)(i - (long)g * NE);
        int dst = load_idx(ei, (long)g * 2 * NE + NE + e, is64);
        atomicAdd(&deg[g * NN + dst], 1.0f);
    }
}

// ---- scatter: one wave per edge, lane d handles feature dim d ---------------
__global__ void scatter_kernel(const float* __restrict__ x, const int* __restrict__ ei,
                               const int* __restrict__ flag, float* __restrict__ agg) {
    int is64 = flag[0];
    int lane = threadIdx.x & 63;
    long wid = ((long)blockIdx.x * blockDim.x + threadIdx.x) >> 6;
    long nwaves = ((long)gridDim.x * blockDim.x) >> 6;
    long total = (long)NG * NE;
    for (long w = wid; w < total; w += nwaves) {
        int g = (int)(w / NE);
        int e = (int)(w - (long)g * NE);
        long ebase = (long)g * 2 * NE;
        int src = load_idx(ei, ebase + e, is64);
        int dst = load_idx(ei, ebase + NE + e, is64);
        float v = x[((long)g * NN + src) * DD + lane];
        atomicAdd(&agg[((long)g * NN + dst) * DD + lane], v);
    }
}

// ---- dense: out[n,:] = elu(mean[n,:]@Wl + x[n,:]@Wr + b), one wave per node -
__global__ void dense_kernel(const float* __restrict__ xin, const float* __restrict__ agg,
                             const float* __restrict__ deg,
                             const float* __restrict__ Wl, const float* __restrict__ Wr,
                             const float* __restrict__ bias, float* __restrict__ out) {
    __shared__ float sWl[DD * DD];
    __shared__ float sWr[DD * DD];
    __shared__ float sb[DD];
    int g = blockIdx.y;
    for (int i = threadIdx.x; i < DD * DD; i += blockDim.x) {
        sWl[i] = Wl[g * DD * DD + i];
        sWr[i] = Wr[g * DD * DD + i];
    }
    if (threadIdx.x < DD) sb[threadIdx.x] = bias[g * DD + threadIdx.x];
    __syncthreads();

    int lane = threadIdx.x & 63;
    int wavesPerBlock = blockDim.x >> 6;
    int wid = (threadIdx.x >> 6) + blockIdx.x * wavesPerBlock;
    int nwaves = gridDim.x * wavesPerBlock;
    for (int n = wid; n < NN; n += nwaves) {
        long base = ((long)g * NN + n) * DD;
        float xr = xin[base + lane];
        float dg = deg[g * NN + n];
        float m = agg[base + lane] / fmaxf(dg, 1.0f);
        float acc = sb[lane];
#pragma unroll
        for (int k = 0; k < DD; ++k) {
            float mk = __shfl(m, k);
            float xk = __shfl(xr, k);
            acc += mk * sWl[k * DD + lane] + xk * sWr[k * DD + lane];
        }
        acc = acc > 0.0f ? acc : expm1f(acc);  // ELU, alpha=1
        out[base + lane] = acc;
    }
}

extern "C" void kernel_launch(void* const* d_in, const int* in_sizes, int n_in,
                              void* d_out, int out_size, void* d_ws, size_t ws_size,
                              hipStream_t stream) {
    const float* x   = (const float*)d_in[0];
    const int*   ei  = (const int*)d_in[1];
    const float* Wl1 = (const float*)d_in[2];
    const float* Wr1 = (const float*)d_in[3];
    const float* b1  = (const float*)d_in[4];
    const float* Wl2 = (const float*)d_in[5];
    const float* Wr2 = (const float*)d_in[6];
    const float* b2  = (const float*)d_in[7];
    float* out = (float*)d_out;

    // ws layout: agg [NG*NN*DD] f32 | deg [NG*NN] f32 | flag [1] i32
    float* agg  = (float*)d_ws;
    float* deg  = agg + (size_t)NG * NN * DD;
    int*   flag = (int*)(deg + (size_t)NG * NN);

    // zero agg + deg each call (harness does not re-poison between replays)
    hipMemsetAsync(agg, 0, ((size_t)NG * NN * DD + (size_t)NG * NN) * sizeof(float), stream);

    detect_kernel<<<1, 64, 0, stream>>>(ei, flag);
    deg_kernel<<<2048, 256, 0, stream>>>(ei, flag, deg);

    // ---- layer 1: h = elu(mean(x)@Wl1 + x@Wr1 + b1), h stored in d_out ----
    scatter_kernel<<<2048, 256, 0, stream>>>(x, ei, flag, agg);
    dim3 dgrid(512, NG);
    dense_kernel<<<dgrid, 256, 0, stream>>>(x, agg, deg, Wl1, Wr1, b1, out);

    // ---- layer 2: out = elu(mean(h)@Wl2 + h@Wr2 + b2), in place ----
    hipMemsetAsync(agg, 0, (size_t)NG * NN * DD * sizeof(float), stream);
    scatter_kernel<<<2048, 256, 0, stream>>>(out, ei, flag, agg);
    dense_kernel<<<dgrid, 256, 0, stream>>>(out, agg, deg, Wl2, Wr2, b2, out);
}

// Round 2
// 1566.357 us; speedup vs baseline: 1.3587x; 1.3587x over previous
//
#include <hip/hip_runtime.h>
#include <hip/hip_bf16.h>
#include <math.h>

#define NG 4
#define NN 50000
#define NE 800000
#define DD 64
#define CAP 64

// ---- int32 vs int64 edge-index detection ----------------------------------
// Reference dtype is int64. If buffer is little-endian int64 with values
// < 2^31, every odd 32-bit word is 0. Genuine int32 random indices in
// [0,50000) cannot have 128 consecutive zero odd words.
__global__ void detect_kernel(const int* __restrict__ ei, int* __restrict__ flag) {
    if (blockIdx.x == 0 && threadIdx.x == 0) {
        int any_nonzero = 0;
        for (int i = 0; i < 128; ++i) any_nonzero |= ei[2 * i + 1];
        flag[0] = (any_nonzero == 0) ? 1 : 0;  // 1 => int64
    }
}

__device__ __forceinline__ int load_idx(const int* __restrict__ ei, long pos, int is64) {
    return is64 ? ei[2 * pos] : ei[pos];
}

// ---- bucket build: cnt[dst]++, bucket[dst][pos] = src ----------------------
__global__ void build_kernel(const int* __restrict__ ei, const int* __restrict__ flag,
                             int* __restrict__ cnt, unsigned short* __restrict__ bucket) {
    int is64 = flag[0];
    long total = (long)NG * NE;
    long stride = (long)gridDim.x * blockDim.x;
    for (long i = (long)blockIdx.x * blockDim.x + threadIdx.x; i < total; i += stride) {
        int g = (int)(i / NE);
        int e = (int)(i - (long)g * NE);
        long ebase = (long)g * 2 * NE;
        int src = load_idx(ei, ebase + e, is64);
        int dst = load_idx(ei, ebase + NE + e, is64);
        int row = g * NN + dst;
        int pos = atomicAdd(&cnt[row], 1);
        if (pos < CAP) bucket[(long)row * CAP + pos] = (unsigned short)src;
    }
}

// ---- load/store helpers (fp32 / bf16) --------------------------------------
__device__ __forceinline__ float ldval(const float* p) { return *p; }
__device__ __forceinline__ float ldval(const __hip_bfloat16* p) { return __bfloat162float(*p); }
__device__ __forceinline__ void stval(float* p, float v) { *p = v; }
__device__ __forceinline__ void stval(__hip_bfloat16* p, float v) { *p = __float2bfloat16(v); }

// ---- fused layer: out[n] = elu(mean_{src->n}(xin[src]) @ Wl + xin[n] @ Wr + b)
// One wave per node; lane = feature dim.
template <typename TIN, typename TOUT>
__global__ void fused_layer_kernel(const TIN* __restrict__ xin,
                                   const int* __restrict__ cnt,
                                   const unsigned short* __restrict__ bucket,
                                   const float* __restrict__ Wl, const float* __restrict__ Wr,
                                   const float* __restrict__ bias, TOUT* __restrict__ out) {
    __shared__ float sWl[DD * DD];
    __shared__ float sWr[DD * DD];
    __shared__ float sb[DD];
    int g = blockIdx.y;
    for (int i = threadIdx.x; i < DD * DD; i += blockDim.x) {
        sWl[i] = Wl[g * DD * DD + i];
        sWr[i] = Wr[g * DD * DD + i];
    }
    if (threadIdx.x < DD) sb[threadIdx.x] = bias[g * DD + threadIdx.x];
    __syncthreads();

    int lane = threadIdx.x & 63;
    int node = blockIdx.x * (blockDim.x >> 6) + (threadIdx.x >> 6);
    if (node >= NN) return;
    int row = g * NN + node;

    int n_e = cnt[row];
    int n_use = n_e < CAP ? n_e : CAP;
    int my_src = (int)bucket[(long)row * CAP + lane];  // coalesced 128B row

    const TIN* xg = xin + (long)g * NN * DD;
    float sum = 0.0f;
    for (int e = 0; e < n_use; ++e) {
        int s = __shfl(my_src, e);
        sum += ldval(&xg[(long)s * DD + lane]);
    }
    float mean = sum / fmaxf((float)n_e, 1.0f);
    float self = ldval(&xg[(long)node * DD + lane]);

    float acc = sb[lane];
#pragma unroll
    for (int k = 0; k < DD; ++k) {
        float mk = __shfl(mean, k);
        float xk = __shfl(self, k);
        acc += mk * sWl[k * DD + lane] + xk * sWr[k * DD + lane];
    }
    acc = acc > 0.0f ? acc : expm1f(acc);  // ELU, alpha=1
    stval(&out[(long)row * DD + lane], acc);
}

extern "C" void kernel_launch(void* const* d_in, const int* in_sizes, int n_in,
                              void* d_out, int out_size, void* d_ws, size_t ws_size,
                              hipStream_t stream) {
    const float* x   = (const float*)d_in[0];
    const int*   ei  = (const int*)d_in[1];
    const float* Wl1 = (const float*)d_in[2];
    const float* Wr1 = (const float*)d_in[3];
    const float* b1  = (const float*)d_in[4];
    const float* Wl2 = (const float*)d_in[5];
    const float* Wr2 = (const float*)d_in[6];
    const float* b2  = (const float*)d_in[7];
    float* out = (float*)d_out;

    // ws layout: cnt [NG*NN] i32 | bucket [NG*NN*CAP] u16 | h [NG*NN*DD] bf16 | flag i32
    // = 0.8 MB + 25.6 MB + 25.6 MB + 4 B = 52,000,004 B (same as round-0 proven usage)
    int* cnt = (int*)d_ws;
    unsigned short* bucket = (unsigned short*)(cnt + (size_t)NG * NN);
    __hip_bfloat16* h = (__hip_bfloat16*)(bucket + (size_t)NG * NN * CAP);
    int* flag = (int*)(h + (size_t)NG * NN * DD);

    hipMemsetAsync(cnt, 0, (size_t)NG * NN * sizeof(int), stream);
    detect_kernel<<<1, 64, 0, stream>>>(ei, flag);
    build_kernel<<<2048, 256, 0, stream>>>(ei, flag, cnt, bucket);

    dim3 grid((NN + 3) / 4, NG);  // 4 waves (nodes) per 256-thread block
    // layer 1: x (f32) -> h (bf16)
    fused_layer_kernel<float, __hip_bfloat16><<<grid, 256, 0, stream>>>(
        x, cnt, bucket, Wl1, Wr1, b1, h);
    // layer 2: h (bf16) -> out (f32)
    fused_layer_kernel<__hip_bfloat16, float><<<grid, 256, 0, stream>>>(
        h, cnt, bucket, Wl2, Wr2, b2, out);
}

// Round 3
// 672.112 us; speedup vs baseline: 3.1665x; 2.3305x over previous
//
#include <hip/hip_runtime.h>
#include <hip/hip_bf16.h>
#include <math.h>

#define NG 4
#define NN 50000
#define NE 800000
#define DD 64
#define CAP 64
#define NT 64           // nodes per block tile

typedef __attribute__((ext_vector_type(8))) short short8;
typedef __attribute__((ext_vector_type(4))) float float4v;
typedef __attribute__((ext_vector_type(8))) float float8v;

__device__ __forceinline__ unsigned short f2b(float f) {
    union { __hip_bfloat16 h; unsigned short u; } cv;
    cv.h = __float2bfloat16(f);
    return cv.u;
}
__device__ __forceinline__ float b2f(unsigned short u) {
    union { unsigned short u; __hip_bfloat16 h; } cv;
    cv.u = u;
    return __bfloat162float(cv.h);
}

// ---- int32 vs int64 edge-index detection: flags bit0 = is64 ----------------
__global__ void detect_kernel(const int* __restrict__ ei, int* __restrict__ flags) {
    if (blockIdx.x == 0 && threadIdx.x == 0) {
        int any_nonzero = 0;
        for (int i = 0; i < 128; ++i) any_nonzero |= ei[2 * i + 1];
        flags[0] = (any_nonzero == 0) ? 1 : 0;
    }
}

__device__ __forceinline__ int load_idx(const int* __restrict__ ei, long pos, int is64) {
    return is64 ? ei[2 * pos] : ei[pos];
}

// ---- MFMA layout probe: flags bit1 = layout verified ------------------------
// A[r][k] = ((r*5+k*3)&31)-15, B[k][c] = ((k*7+c*11)&31)-15 (asymmetric ints,
// exact in bf16/f32). Verifies A,B and C/D lane mappings end-to-end.
__global__ void probe_kernel(int* __restrict__ flags) {
    __shared__ alignas(16) unsigned short A[16 * 32];
    __shared__ unsigned short B[32 * 16];
    int t = threadIdx.x;
    for (int i = t; i < 512; i += 64) {
        int r = i >> 5, k = i & 31;
        A[i] = f2b((float)(((r * 5 + k * 3) & 31) - 15));
        int kk = i >> 4, c = i & 15;
        B[i] = f2b((float)(((kk * 7 + c * 11) & 31) - 15));
    }
    __syncthreads();
    short8 a = *(const short8*)&A[(t & 15) * 32 + (t >> 4) * 8];
    int c = t & 15, kb = (t >> 4) * 8;
    short8 b;
    for (int j = 0; j < 8; ++j) b[j] = (short)B[(kb + j) * 16 + c];
    float4v acc = {0.f, 0.f, 0.f, 0.f};
    acc = __builtin_amdgcn_mfma_f32_16x16x32_bf16(a, b, acc, 0, 0, 0);
    int ok = 1;
    for (int reg = 0; reg < 4; ++reg) {
        int row = (t >> 4) * 4 + reg;
        float ref = 0.f;
        for (int k = 0; k < 32; ++k)
            ref += (float)(((row * 5 + k * 3) & 31) - 15) *
                   (float)(((k * 7 + c * 11) & 31) - 15);
        if (acc[reg] != ref) ok = 0;
    }
    unsigned long long vote = __ballot(ok);
    if (t == 0) atomicOr(&flags[0], (vote == ~0ULL) ? 2 : 0);
}

// ---- bucket build ----------------------------------------------------------
__global__ void build_kernel(const int* __restrict__ ei, const int* __restrict__ flags,
                             int* __restrict__ cnt, unsigned short* __restrict__ bucket) {
    int is64 = flags[0] & 1;
    long total = (long)NG * NE;
    long stride = (long)gridDim.x * blockDim.x;
    for (long i = (long)blockIdx.x * blockDim.x + threadIdx.x; i < total; i += stride) {
        int g = (int)(i / NE);
        int e = (int)(i - (long)g * NE);
        long ebase = (long)g * 2 * NE;
        int src = load_idx(ei, ebase + e, is64);
        int dst = load_idx(ei, ebase + NE + e, is64);
        int row = g * NN + dst;
        int pos = atomicAdd(&cnt[row], 1);
        if (pos < CAP) bucket[(long)row * CAP + pos] = (unsigned short)src;
    }
}

// ---- convert x f32 -> bf16 -------------------------------------------------
__global__ void convert_kernel(const float* __restrict__ x, unsigned short* __restrict__ xb) {
    long total = (long)NG * NN * DD / 4;
    long stride = (long)gridDim.x * blockDim.x;
    const float4* src = (const float4*)x;
    unsigned long long* dst = (unsigned long long*)xb;
    for (long i = (long)blockIdx.x * blockDim.x + threadIdx.x; i < total; i += stride) {
        float4 v = src[i];
        unsigned long long p = (unsigned long long)f2b(v.x)
                             | ((unsigned long long)f2b(v.y) << 16)
                             | ((unsigned long long)f2b(v.z) << 32)
                             | ((unsigned long long)f2b(v.w) << 48);
        dst[i] = p;
    }
}

// ---- fused gather + MFMA layer ---------------------------------------------
// Block = 64-node tile of one graph. Wave w: gathers means for rows 16w..16w+15
// into XOR-swizzled LDS, then computes D[16x64] = mean@Wl + x@Wr + b via
// 16 mfma_16x16x32_bf16, ELU, LDS-roundtrip, coalesced store.
// graph = (blockIdx.x & 7) >> 1  => each graph pinned to one XCD pair.
template <int LAYER>  // 0: out = h (bf16), 1: out = d_out (f32)
__launch_bounds__(256, 4)
__global__ void sage_mfma_kernel(const unsigned short* __restrict__ xin,
                                 const int* __restrict__ cnt,
                                 const unsigned short* __restrict__ bucket,
                                 const float* __restrict__ Wl, const float* __restrict__ Wr,
                                 const float* __restrict__ bias, void* __restrict__ outp,
                                 const int* __restrict__ flags) {
    if (!(flags[0] & 2)) return;
    __shared__ alignas(16) unsigned short sWT[2 * DD * DD];  // [m][col][k^swz] bf16
    __shared__ alignas(32) float sM[NT * DD];                // [row][feat^swz] f32

    int s = blockIdx.x & 7, tb = blockIdx.x >> 3;
    int g = s >> 1;
    int tile = tb * 2 + (s & 1);          // 0..781
    int base = tile * NT;
    long gn0 = (long)g * NN;

    // stage W^T (bf16, swizzled: u16 index k ^ ((col&7)<<3))
    for (int i = threadIdx.x; i < 2 * DD * DD; i += 256) {
        int m = i >> 12, rem = i & 4095, k = rem >> 6, col = rem & 63;
        float wv = (m == 0 ? Wl : Wr)[(long)g * DD * DD + rem];
        sWT[m * DD * DD + col * DD + (k ^ ((col & 7) << 3))] = f2b(wv);
    }
    __syncthreads();

    int lane = threadIdx.x & 63;
    int w = threadIdx.x >> 6;

    // ---- gather phase: means for this wave's 16 rows ----
#pragma unroll 1
    for (int j = 0; j < 16; ++j) {
        int rl = w * 16 + j;
        int node = base + rl;
        float mean = 0.f;
        if (node < NN) {
            long row = gn0 + node;
            int ne = cnt[row];
            int nuse = ne < CAP ? ne : CAP;
            int msrc = (int)bucket[row * CAP + lane];  // coalesced 128B
            float s0 = 0.f, s1 = 0.f, s2 = 0.f, s3 = 0.f;
            int e = 0;
            for (; e + 4 <= nuse; e += 4) {
                int a0 = __shfl(msrc, e), a1 = __shfl(msrc, e + 1);
                int a2 = __shfl(msrc, e + 2), a3 = __shfl(msrc, e + 3);
                s0 += b2f(xin[(gn0 + a0) * DD + lane]);
                s1 += b2f(xin[(gn0 + a1) * DD + lane]);
                s2 += b2f(xin[(gn0 + a2) * DD + lane]);
                s3 += b2f(xin[(gn0 + a3) * DD + lane]);
            }
            for (; e < nuse; ++e) {
                int a0 = __shfl(msrc, e);
                s0 += b2f(xin[(gn0 + a0) * DD + lane]);
            }
            mean = ((s0 + s1) + (s2 + s3)) / fmaxf((float)ne, 1.f);
        }
        sM[rl * DD + (lane ^ ((rl & 7) << 3))] = mean;  // own rows, no barrier
    }

    // ---- MFMA phase ----
    int arow = w * 16 + (lane & 15);
    int kb = (lane >> 4) * 8;
    int selfrow = base + arow; if (selfrow > NN - 1) selfrow = NN - 1;  // clamp OOB tail
    short8 am[2], ax[2];
    for (int ss = 0; ss < 2; ++ss) {
        int f0 = (kb + 32 * ss) ^ ((arow & 7) << 3);
        float8v mv = *(const float8v*)&sM[arow * DD + f0];
        short8 t;
        for (int j = 0; j < 8; ++j) t[j] = (short)f2b(mv[j]);
        am[ss] = t;
        ax[ss] = *(const short8*)&xin[(gn0 + selfrow) * DD + kb + 32 * ss];
    }

    float4v acc[4];
    for (int c = 0; c < 4; ++c) {
        float b = bias[g * DD + c * 16 + (lane & 15)];
        acc[c] = {b, b, b, b};
    }
    for (int c = 0; c < 4; ++c) {
        int col = c * 16 + (lane & 15);
        int cswz = (col & 7) << 3;
        for (int ss = 0; ss < 2; ++ss) {
            short8 bl = *(const short8*)&sWT[0 * DD * DD + col * DD + ((kb + 32 * ss) ^ cswz)];
            acc[c] = __builtin_amdgcn_mfma_f32_16x16x32_bf16(am[ss], bl, acc[c], 0, 0, 0);
        }
        for (int ss = 0; ss < 2; ++ss) {
            short8 br = *(const short8*)&sWT[1 * DD * DD + col * DD + ((kb + 32 * ss) ^ cswz)];
            acc[c] = __builtin_amdgcn_mfma_f32_16x16x32_bf16(ax[ss], br, acc[c], 0, 0, 0);
        }
    }

    // ELU, write D back to sM (own rows)
    for (int c = 0; c < 4; ++c) {
        int col = c * 16 + (lane & 15);
        for (int r = 0; r < 4; ++r) {
            float v = acc[c][r];
            v = v > 0.f ? v : expm1f(v);
            int rw = w * 16 + (lane >> 4) * 4 + r;
            sM[rw * DD + (col ^ ((rw & 7) << 3))] = v;
        }
    }
    // coalesced store (own rows; same-wave LDS ordering)
#pragma unroll 1
    for (int j = 0; j < 16; ++j) {
        int rl = w * 16 + j;
        int node = base + rl;
        if (node >= NN) continue;
        float v = sM[rl * DD + (lane ^ ((rl & 7) << 3))];
        if (LAYER == 0)
            ((unsigned short*)outp)[(gn0 + node) * DD + lane] = f2b(v);
        else
            ((float*)outp)[(gn0 + node) * DD + lane] = v;
    }
}

// ---- fallback (proven round-2 structure), runs only if probe failed --------
template <int LAYER>
__global__ void fallback_kernel(const unsigned short* __restrict__ xin,
                                const int* __restrict__ cnt,
                                const unsigned short* __restrict__ bucket,
                                const float* __restrict__ Wl, const float* __restrict__ Wr,
                                const float* __restrict__ bias, void* __restrict__ outp,
                                const int* __restrict__ flags) {
    if (flags[0] & 2) return;
    __shared__ float sWl[DD * DD];
    __shared__ float sWr[DD * DD];
    __shared__ float sb[DD];
    int g = blockIdx.y;
    for (int i = threadIdx.x; i < DD * DD; i += blockDim.x) {
        sWl[i] = Wl[g * DD * DD + i];
        sWr[i] = Wr[g * DD * DD + i];
    }
    if (threadIdx.x < DD) sb[threadIdx.x] = bias[g * DD + threadIdx.x];
    __syncthreads();
    int lane = threadIdx.x & 63;
    int node = blockIdx.x * (blockDim.x >> 6) + (threadIdx.x >> 6);
    if (node >= NN) return;
    long row = (long)g * NN + node;
    int ne = cnt[row];
    int nuse = ne < CAP ? ne : CAP;
    int msrc = (int)bucket[row * CAP + lane];
    long gn0 = (long)g * NN;
    float sum = 0.f;
    for (int e = 0; e < nuse; ++e) {
        int a0 = __shfl(msrc, e);
        sum += b2f(xin[(gn0 + a0) * DD + lane]);
    }
    float mean = sum / fmaxf((float)ne, 1.f);
    float self = b2f(xin[row * DD + lane]);
    float acc = sb[lane];
#pragma unroll
    for (int k = 0; k < DD; ++k) {
        float mk = __shfl(mean, k);
        float xk = __shfl(self, k);
        acc += mk * sWl[k * DD + lane] + xk * sWr[k * DD + lane];
    }
    acc = acc > 0.f ? acc : expm1f(acc);
    if (LAYER == 0) ((unsigned short*)outp)[row * DD + lane] = f2b(acc);
    else            ((float*)outp)[row * DD + lane] = acc;
}

extern "C" void kernel_launch(void* const* d_in, const int* in_sizes, int n_in,
                              void* d_out, int out_size, void* d_ws, size_t ws_size,
                              hipStream_t stream) {
    const float* x   = (const float*)d_in[0];
    const int*   ei  = (const int*)d_in[1];
    const float* Wl1 = (const float*)d_in[2];
    const float* Wr1 = (const float*)d_in[3];
    const float* b1  = (const float*)d_in[4];
    const float* Wl2 = (const float*)d_in[5];
    const float* Wr2 = (const float*)d_in[6];
    const float* b2  = (const float*)d_in[7];
    float* out = (float*)d_out;

    // ws: cnt i32[200000] | bucket u16[200000*64] | h u16[200000*64] | flags i32
    // = 800000 + 25600000 + 25600000 + 4 = 52,000,004 B (proven budget)
    int* cnt = (int*)d_ws;
    unsigned short* bucket = (unsigned short*)(cnt + (size_t)NG * NN);
    unsigned short* h = bucket + (size_t)NG * NN * CAP;
    int* flags = (int*)(h + (size_t)NG * NN * DD);
    // xb (x as bf16, 25.6 MB) lives in d_out's first half; dead before final write
    unsigned short* xb = (unsigned short*)d_out;

    hipMemsetAsync(cnt, 0, (size_t)NG * NN * sizeof(int), stream);
    detect_kernel<<<1, 64, 0, stream>>>(ei, flags);
    probe_kernel<<<1, 64, 0, stream>>>(flags);
    build_kernel<<<2048, 256, 0, stream>>>(ei, flags, cnt, bucket);
    convert_kernel<<<2048, 256, 0, stream>>>(x, xb);

    const int grid = 391 * 8;  // 782 tiles x 4 graphs, XCD-pair swizzled
    dim3 fgrid((NN + 3) / 4, NG);
    // layer 1: xb -> h (bf16)
    sage_mfma_kernel<0><<<grid, 256, 0, stream>>>(xb, cnt, bucket, Wl1, Wr1, b1, h, flags);
    fallback_kernel<0><<<fgrid, 256, 0, stream>>>(xb, cnt, bucket, Wl1, Wr1, b1, h, flags);
    // layer 2: h -> out (f32)
    sage_mfma_kernel<1><<<grid, 256, 0, stream>>>(h, cnt, bucket, Wl2, Wr2, b2, out, flags);
    fallback_kernel<1><<<fgrid, 256, 0, stream>>>(h, cnt, bucket, Wl2, Wr2, b2, out, flags);
}

// Round 4
// 540.095 us; speedup vs baseline: 3.9404x; 1.2444x over previous
//
#include <hip/hip_runtime.h>
#include <hip/hip_bf16.h>
#include <math.h>

#define NG 4
#define NN 50000
#define NE 800000
#define DD 64
#define CAP 64
#define NT 64           // nodes per block tile

typedef __attribute__((ext_vector_type(8))) short short8;
typedef __attribute__((ext_vector_type(4))) float float4v;
typedef __attribute__((ext_vector_type(8))) float float8v;

__device__ __forceinline__ unsigned short f2b(float f) {
    union { __hip_bfloat16 h; unsigned short u; } cv;
    cv.h = __float2bfloat16(f);
    return cv.u;
}
__device__ __forceinline__ float b2f(unsigned short u) {
    union { unsigned short u; __hip_bfloat16 h; } cv;
    cv.u = u;
    return __bfloat162float(cv.h);
}

// ---- init: detect int64 (bit0) + verify MFMA layout (bit1), one block ------
__global__ void init_kernel(const int* __restrict__ ei, int* __restrict__ flags) {
    __shared__ alignas(16) unsigned short A[16 * 32];
    __shared__ unsigned short B[32 * 16];
    int t = threadIdx.x;
    // detect: int64 little-endian => odd 32-bit words all zero
    int any_nonzero = 0;
    for (int i = t; i < 128; i += 64) any_nonzero |= ei[2 * i + 1];
    unsigned long long nz = __ballot(any_nonzero != 0);
    int is64 = (nz == 0ULL) ? 1 : 0;
    // probe: A[r][k]=((r*5+k*3)&31)-15, B[k][c]=((k*7+c*11)&31)-15 (exact ints)
    for (int i = t; i < 512; i += 64) {
        int r = i >> 5, k = i & 31;
        A[i] = f2b((float)(((r * 5 + k * 3) & 31) - 15));
        int kk = i >> 4, c = i & 15;
        B[i] = f2b((float)(((kk * 7 + c * 11) & 31) - 15));
    }
    __syncthreads();
    short8 a = *(const short8*)&A[(t & 15) * 32 + (t >> 4) * 8];
    int c = t & 15, kb = (t >> 4) * 8;
    short8 b;
    for (int j = 0; j < 8; ++j) b[j] = (short)B[(kb + j) * 16 + c];
    float4v acc = {0.f, 0.f, 0.f, 0.f};
    acc = __builtin_amdgcn_mfma_f32_16x16x32_bf16(a, b, acc, 0, 0, 0);
    int ok = 1;
    for (int reg = 0; reg < 4; ++reg) {
        int row = (t >> 4) * 4 + reg;
        float ref = 0.f;
        for (int k = 0; k < 32; ++k)
            ref += (float)(((row * 5 + k * 3) & 31) - 15) *
                   (float)(((k * 7 + c * 11) & 31) - 15);
        if (acc[reg] != ref) ok = 0;
    }
    unsigned long long vote = __ballot(ok);
    if (t == 0) flags[0] = is64 | ((vote == ~0ULL) ? 2 : 0);
}

__device__ __forceinline__ int load_idx(const int* __restrict__ ei, long pos, int is64) {
    return is64 ? ei[2 * pos] : ei[pos];
}

// ---- bucket build, XCD-local -----------------------------------------------
// Slot s = blockIdx.x & 7 (round-robin -> XCD s). Slot handles graph s>>1,
// dst range [ (s&1)*25000, +25000 ). Write footprint per slot = 3.2MB bucket
// + 0.1MB cnt => resident in that XCD's 4MB L2; one write-back per line.
__global__ void build_kernel(const int* __restrict__ ei, const int* __restrict__ flags,
                             int* __restrict__ cnt, unsigned short* __restrict__ bucket) {
    int is64 = flags[0] & 1;
    int s = blockIdx.x & 7;
    int g = s >> 1;
    int lo = (s & 1) * (NN / 2), hi = lo + (NN / 2);
    int bsl = blockIdx.x >> 3;
    int nthreads = (gridDim.x >> 3) * blockDim.x;
    int tid = bsl * blockDim.x + threadIdx.x;
    long ebase = (long)g * 2 * NE;
    for (int e = tid; e < NE; e += nthreads) {
        int dst = load_idx(ei, ebase + NE + e, is64);
        if (dst < lo || dst >= hi) continue;
        int src = load_idx(ei, ebase + e, is64);
        int row = g * NN + dst;
        int pos = atomicAdd(&cnt[row], 1);
        if (pos < CAP) bucket[(long)row * CAP + pos] = (unsigned short)src;
    }
}

// ---- convert x f32 -> bf16 -------------------------------------------------
__global__ void convert_kernel(const float* __restrict__ x, unsigned short* __restrict__ xb) {
    long total = (long)NG * NN * DD / 4;
    long stride = (long)gridDim.x * blockDim.x;
    const float4* src = (const float4*)x;
    unsigned long long* dst = (unsigned long long*)xb;
    for (long i = (long)blockIdx.x * blockDim.x + threadIdx.x; i < total; i += stride) {
        float4 v = src[i];
        unsigned long long p = (unsigned long long)f2b(v.x)
                             | ((unsigned long long)f2b(v.y) << 16)
                             | ((unsigned long long)f2b(v.z) << 32)
                             | ((unsigned long long)f2b(v.w) << 48);
        dst[i] = p;
    }
}

// ---- fused gather + MFMA layer ---------------------------------------------
// Block = 64-node tile; wave w gathers means for rows 16w..16w+15 into
// XOR-swizzled LDS, then 16x mfma_16x16x32_bf16 for D = mean@Wl + x@Wr + b,
// ELU, coalesced store. graph = (blockIdx.x&7)>>1 => graph pinned to XCD pair.
template <int LAYER>  // 0: out = h (bf16), 1: out = d_out (f32)
__launch_bounds__(256, 4)
__global__ void sage_mfma_kernel(const unsigned short* __restrict__ xin,
                                 const int* __restrict__ cnt,
                                 const unsigned short* __restrict__ bucket,
                                 const float* __restrict__ Wl, const float* __restrict__ Wr,
                                 const float* __restrict__ bias, void* __restrict__ outp,
                                 const int* __restrict__ flags) {
    if (!(flags[0] & 2)) return;
    __shared__ alignas(16) unsigned short sWT[2 * DD * DD];  // [m][col][k^swz] bf16
    __shared__ alignas(32) float sM[NT * DD];                // [row][feat^swz] f32

    int s = blockIdx.x & 7, tb = blockIdx.x >> 3;
    int g = s >> 1;
    int tile = tb * 2 + (s & 1);          // 0..781
    int base = tile * NT;
    long gn0 = (long)g * NN;

    // stage W^T (bf16, swizzled: u16 index k ^ ((col&7)<<3))
    for (int i = threadIdx.x; i < 2 * DD * DD; i += 256) {
        int m = i >> 12, rem = i & 4095, k = rem >> 6, col = rem & 63;
        float wv = (m == 0 ? Wl : Wr)[(long)g * DD * DD + rem];
        sWT[m * DD * DD + col * DD + (k ^ ((col & 7) << 3))] = f2b(wv);
    }
    __syncthreads();

    int lane = threadIdx.x & 63;
    int w = threadIdx.x >> 6;

    // ---- gather phase: means for this wave's 16 rows ----
#pragma unroll 1
    for (int j = 0; j < 16; ++j) {
        int rl = w * 16 + j;
        int node = base + rl;
        float mean = 0.f;
        if (node < NN) {
            long row = gn0 + node;
            int ne = cnt[row];
            int nuse = ne < CAP ? ne : CAP;
            int msrc = (int)bucket[row * CAP + lane];  // coalesced 128B
            float s0 = 0.f, s1 = 0.f, s2 = 0.f, s3 = 0.f;
            int e = 0;
            for (; e + 4 <= nuse; e += 4) {
                int a0 = __shfl(msrc, e), a1 = __shfl(msrc, e + 1);
                int a2 = __shfl(msrc, e + 2), a3 = __shfl(msrc, e + 3);
                s0 += b2f(xin[(gn0 + a0) * DD + lane]);
                s1 += b2f(xin[(gn0 + a1) * DD + lane]);
                s2 += b2f(xin[(gn0 + a2) * DD + lane]);
                s3 += b2f(xin[(gn0 + a3) * DD + lane]);
            }
            for (; e < nuse; ++e) {
                int a0 = __shfl(msrc, e);
                s0 += b2f(xin[(gn0 + a0) * DD + lane]);
            }
            mean = ((s0 + s1) + (s2 + s3)) / fmaxf((float)ne, 1.f);
        }
        sM[rl * DD + (lane ^ ((rl & 7) << 3))] = mean;  // own rows, no barrier
    }

    // ---- MFMA phase ----
    int arow = w * 16 + (lane & 15);
    int kb = (lane >> 4) * 8;
    int selfrow = base + arow; if (selfrow > NN - 1) selfrow = NN - 1;  // clamp OOB tail
    short8 am[2], ax[2];
    for (int ss = 0; ss < 2; ++ss) {
        int f0 = (kb + 32 * ss) ^ ((arow & 7) << 3);
        float8v mv = *(const float8v*)&sM[arow * DD + f0];
        short8 t;
        for (int j = 0; j < 8; ++j) t[j] = (short)f2b(mv[j]);
        am[ss] = t;
        ax[ss] = *(const short8*)&xin[(gn0 + selfrow) * DD + kb + 32 * ss];
    }

    float4v acc[4];
    for (int c = 0; c < 4; ++c) {
        float b = bias[g * DD + c * 16 + (lane & 15)];
        acc[c] = {b, b, b, b};
    }
    for (int c = 0; c < 4; ++c) {
        int col = c * 16 + (lane & 15);
        int cswz = (col & 7) << 3;
        for (int ss = 0; ss < 2; ++ss) {
            short8 bl = *(const short8*)&sWT[0 * DD * DD + col * DD + ((kb + 32 * ss) ^ cswz)];
            acc[c] = __builtin_amdgcn_mfma_f32_16x16x32_bf16(am[ss], bl, acc[c], 0, 0, 0);
        }
        for (int ss = 0; ss < 2; ++ss) {
            short8 br = *(const short8*)&sWT[1 * DD * DD + col * DD + ((kb + 32 * ss) ^ cswz)];
            acc[c] = __builtin_amdgcn_mfma_f32_16x16x32_bf16(ax[ss], br, acc[c], 0, 0, 0);
        }
    }

    // ELU, write D back to sM (own rows)
    for (int c = 0; c < 4; ++c) {
        int col = c * 16 + (lane & 15);
        for (int r = 0; r < 4; ++r) {
            float v = acc[c][r];
            v = v > 0.f ? v : expm1f(v);
            int rw = w * 16 + (lane >> 4) * 4 + r;
            sM[rw * DD + (col ^ ((rw & 7) << 3))] = v;
        }
    }
    // coalesced store (own rows; same-wave LDS ordering)
#pragma unroll 1
    for (int j = 0; j < 16; ++j) {
        int rl = w * 16 + j;
        int node = base + rl;
        if (node >= NN) continue;
        float v = sM[rl * DD + (lane ^ ((rl & 7) << 3))];
        if (LAYER == 0)
            ((unsigned short*)outp)[(gn0 + node) * DD + lane] = f2b(v);
        else
            ((float*)outp)[(gn0 + node) * DD + lane] = v;
    }
}

// ---- fallback (proven shfl-matvec), grid-stride, runs only if probe failed --
template <int LAYER>
__global__ void fallback_kernel(const unsigned short* __restrict__ xin,
                                const int* __restrict__ cnt,
                                const unsigned short* __restrict__ bucket,
                                const float* __restrict__ Wl, const float* __restrict__ Wr,
                                const float* __restrict__ bias, void* __restrict__ outp,
                                const int* __restrict__ flags) {
    if (flags[0] & 2) return;
    __shared__ float sWl[DD * DD];
    __shared__ float sWr[DD * DD];
    __shared__ float sb[DD];
    int g = blockIdx.y;
    for (int i = threadIdx.x; i < DD * DD; i += blockDim.x) {
        sWl[i] = Wl[g * DD * DD + i];
        sWr[i] = Wr[g * DD * DD + i];
    }
    if (threadIdx.x < DD) sb[threadIdx.x] = bias[g * DD + threadIdx.x];
    __syncthreads();
    int lane = threadIdx.x & 63;
    int wpb = blockDim.x >> 6;
    long gn0 = (long)g * NN;
    for (int node = blockIdx.x * wpb + (threadIdx.x >> 6); node < NN;
         node += gridDim.x * wpb) {
        long row = gn0 + node;
        int ne = cnt[row];
        int nuse = ne < CAP ? ne : CAP;
        int msrc = (int)bucket[row * CAP + lane];
        float sum = 0.f;
        for (int e = 0; e < nuse; ++e) {
            int a0 = __shfl(msrc, e);
            sum += b2f(xin[(gn0 + a0) * DD + lane]);
        }
        float mean = sum / fmaxf((float)ne, 1.f);
        float self = b2f(xin[row * DD + lane]);
        float acc = sb[lane];
#pragma unroll
        for (int k = 0; k < DD; ++k) {
            float mk = __shfl(mean, k);
            float xk = __shfl(self, k);
            acc += mk * sWl[k * DD + lane] + xk * sWr[k * DD + lane];
        }
        acc = acc > 0.f ? acc : expm1f(acc);
        if (LAYER == 0) ((unsigned short*)outp)[row * DD + lane] = f2b(acc);
        else            ((float*)outp)[row * DD + lane] = acc;
    }
}

extern "C" void kernel_launch(void* const* d_in, const int* in_sizes, int n_in,
                              void* d_out, int out_size, void* d_ws, size_t ws_size,
                              hipStream_t stream) {
    const float* x   = (const float*)d_in[0];
    const int*   ei  = (const int*)d_in[1];
    const float* Wl1 = (const float*)d_in[2];
    const float* Wr1 = (const float*)d_in[3];
    const float* b1  = (const float*)d_in[4];
    const float* Wl2 = (const float*)d_in[5];
    const float* Wr2 = (const float*)d_in[6];
    const float* b2  = (const float*)d_in[7];
    float* out = (float*)d_out;

    // ws: cnt i32[200000] | bucket u16[200000*64] | h u16[200000*64] | flags i32
    // = 800000 + 25600000 + 25600000 + 4 = 52,000,004 B (proven budget)
    int* cnt = (int*)d_ws;
    unsigned short* bucket = (unsigned short*)(cnt + (size_t)NG * NN);
    unsigned short* h = bucket + (size_t)NG * NN * CAP;
    int* flags = (int*)(h + (size_t)NG * NN * DD);
    // xb (x as bf16, 25.6 MB) lives in d_out's first half; dead before final write
    unsigned short* xb = (unsigned short*)d_out;

    hipMemsetAsync(cnt, 0, (size_t)NG * NN * sizeof(int), stream);
    init_kernel<<<1, 64, 0, stream>>>(ei, flags);
    build_kernel<<<2048, 256, 0, stream>>>(ei, flags, cnt, bucket);
    convert_kernel<<<2048, 256, 0, stream>>>(x, xb);

    const int grid = 391 * 8;  // 782 tiles x 4 graphs, XCD-swizzled
    dim3 fgrid(512, NG);
    // layer 1: xb -> h (bf16)
    sage_mfma_kernel<0><<<grid, 256, 0, stream>>>(xb, cnt, bucket, Wl1, Wr1, b1, h, flags);
    fallback_kernel<0><<<fgrid, 256, 0, stream>>>(xb, cnt, bucket, Wl1, Wr1, b1, h, flags);
    // layer 2: h -> out (f32)
    sage_mfma_kernel<1><<<grid, 256, 0, stream>>>(h, cnt, bucket, Wl2, Wr2, b2, out, flags);
    fallback_kernel<1><<<fgrid, 256, 0, stream>>>(h, cnt, bucket, Wl2, Wr2, b2, out, flags);
}

// Round 5
// 428.724 us; speedup vs baseline: 4.9640x; 1.2598x over previous
//
#include <hip/hip_runtime.h>
#include <hip/hip_bf16.h>
#include <math.h>

#define NG 4
#define NN 50000
#define NE 800000
#define DD 64
#define CAP 64
#define NT 64           // nodes per block tile
#define NTILE 391       // tiles per (graph, half): 391*64 = 25024 >= 25000

typedef __attribute__((ext_vector_type(8))) short short8;
typedef __attribute__((ext_vector_type(4))) float float4v;

__device__ __forceinline__ unsigned short f2b(float f) {
    union { __hip_bfloat16 h; unsigned short u; } cv;
    cv.h = __float2bfloat16(f);
    return cv.u;
}
__device__ __forceinline__ float b2f(unsigned short u) {
    union { unsigned short u; __hip_bfloat16 h; } cv;
    cv.u = u;
    return __bfloat162float(cv.h);
}

// ---- init: detect int64 (bit0) + verify MFMA layout (bit1), one block ------
__global__ void init_kernel(const int* __restrict__ ei, int* __restrict__ flags) {
    __shared__ alignas(16) unsigned short A[16 * 32];
    __shared__ unsigned short B[32 * 16];
    int t = threadIdx.x;
    int any_nonzero = 0;
    for (int i = t; i < 128; i += 64) any_nonzero |= ei[2 * i + 1];
    unsigned long long nz = __ballot(any_nonzero != 0);
    int is64 = (nz == 0ULL) ? 1 : 0;
    for (int i = t; i < 512; i += 64) {
        int r = i >> 5, k = i & 31;
        A[i] = f2b((float)(((r * 5 + k * 3) & 31) - 15));
        int kk = i >> 4, c = i & 15;
        B[i] = f2b((float)(((kk * 7 + c * 11) & 31) - 15));
    }
    __syncthreads();
    short8 a = *(const short8*)&A[(t & 15) * 32 + (t >> 4) * 8];
    int c = t & 15, kb = (t >> 4) * 8;
    short8 b;
    for (int j = 0; j < 8; ++j) b[j] = (short)B[(kb + j) * 16 + c];
    float4v acc = {0.f, 0.f, 0.f, 0.f};
    acc = __builtin_amdgcn_mfma_f32_16x16x32_bf16(a, b, acc, 0, 0, 0);
    int ok = 1;
    for (int reg = 0; reg < 4; ++reg) {
        int row = (t >> 4) * 4 + reg;
        float ref = 0.f;
        for (int k = 0; k < 32; ++k)
            ref += (float)(((row * 5 + k * 3) & 31) - 15) *
                   (float)(((k * 7 + c * 11) & 31) - 15);
        if (acc[reg] != ref) ok = 0;
    }
    unsigned long long vote = __ballot(ok);
    if (t == 0) flags[0] = is64 | ((vote == ~0ULL) ? 2 : 0);
}

__device__ __forceinline__ int load_idx(const int* __restrict__ ei, long pos, int is64) {
    return is64 ? ei[2 * pos] : ei[pos];
}

// ---- bucket build, XCD-local (slot s: graph s>>1, dst half s&1) ------------
__global__ void build_kernel(const int* __restrict__ ei, const int* __restrict__ flags,
                             int* __restrict__ cnt, unsigned short* __restrict__ bucket) {
    int is64 = flags[0] & 1;
    int s = blockIdx.x & 7;
    int g = s >> 1;
    int lo = (s & 1) * (NN / 2), hi = lo + (NN / 2);
    int bsl = blockIdx.x >> 3;
    int nthreads = (gridDim.x >> 3) * blockDim.x;
    int tid = bsl * blockDim.x + threadIdx.x;
    long ebase = (long)g * 2 * NE;
    for (int e = tid; e < NE; e += nthreads) {
        int dst = load_idx(ei, ebase + NE + e, is64);
        if (dst < lo || dst >= hi) continue;
        int src = load_idx(ei, ebase + e, is64);
        int row = g * NN + dst;
        int pos = atomicAdd(&cnt[row], 1);
        if (pos < CAP) bucket[(long)row * CAP + pos] = (unsigned short)src;
    }
}

// ---- convert x f32 -> bf16 -------------------------------------------------
__global__ void convert_kernel(const float* __restrict__ x, unsigned short* __restrict__ xb) {
    long total = (long)NG * NN * DD / 4;
    long stride = (long)gridDim.x * blockDim.x;
    const float4* src = (const float4*)x;
    unsigned long long* dst = (unsigned long long*)xb;
    for (long i = (long)blockIdx.x * blockDim.x + threadIdx.x; i < total; i += stride) {
        float4 v = src[i];
        unsigned long long p = (unsigned long long)f2b(v.x)
                             | ((unsigned long long)f2b(v.y) << 16)
                             | ((unsigned long long)f2b(v.z) << 32)
                             | ((unsigned long long)f2b(v.w) << 48);
        dst[i] = p;
    }
}

// ---- fused gather + MFMA layer ---------------------------------------------
// Block = 64-node tile; slot s = blockIdx&7 -> XCD s, graph s>>1, node half s&1
// (matches build partition -> bucket/cnt L2-local). Wave w gathers bf16 means
// for rows 16w..16w+15 into swizzled LDS, 16x mfma_16x16x32_bf16, ELU,
// direct register->global stores (64B segments for f32).
template <int LAYER>  // 0: out = h (bf16), 1: out = d_out (f32)
__launch_bounds__(256, 6)
__global__ void sage_mfma_kernel(const unsigned short* __restrict__ xin,
                                 const int* __restrict__ cnt,
                                 const unsigned short* __restrict__ bucket,
                                 const float* __restrict__ Wl, const float* __restrict__ Wr,
                                 const float* __restrict__ bias, void* __restrict__ outp,
                                 const int* __restrict__ flags) {
    if (!(flags[0] & 2)) return;
    __shared__ alignas(16) unsigned short sWT[2 * DD * DD];  // [m][col][k^swz] bf16, 16KB
    __shared__ alignas(16) unsigned short sM[NT * DD];       // [row][lane^swz] bf16, 8KB

    int s = blockIdx.x & 7, tb = blockIdx.x >> 3;
    int g = s >> 1;
    int tile = (s & 1) * NTILE + tb;      // 0..781, halves match build partition
    int base = tile * NT;
    long gn0 = (long)g * NN;

    // stage W^T swizzled, conflict-free: thread -> (m, k-octet ko, col).
    // Global: 8 coalesced row reads; LDS: one b128 write, 8-lane groups cover
    // all 32 banks.
    for (int i = threadIdx.x; i < 1024; i += 256) {
        int col = i & 63, ko = (i >> 6) & 7, m = i >> 9;
        const float* Wsrc = (m == 0 ? Wl : Wr) + (long)g * DD * DD;
        short8 t;
#pragma unroll
        for (int j = 0; j < 8; ++j)
            t[j] = (short)f2b(Wsrc[(ko * 8 + j) * DD + col]);
        *(short8*)&sWT[m * DD * DD + col * DD + ((ko * 8) ^ ((col & 7) << 3))] = t;
    }
    __syncthreads();

    int lane = threadIdx.x & 63;
    int w = threadIdx.x >> 6;

    // ---- gather phase: bf16 means for this wave's 16 rows ----
#pragma unroll 1
    for (int j = 0; j < 16; ++j) {
        int rl = w * 16 + j;
        int node = base + rl;
        float mean = 0.f;
        if (node < NN) {
            long row = gn0 + node;
            int ne = cnt[row];
            int nuse = ne < CAP ? ne : CAP;
            int msrc = (int)bucket[row * CAP + lane];  // coalesced 128B
            float s0 = 0.f, s1 = 0.f, s2 = 0.f, s3 = 0.f;
            int e = 0;
            for (; e + 4 <= nuse; e += 4) {
                int a0 = __shfl(msrc, e), a1 = __shfl(msrc, e + 1);
                int a2 = __shfl(msrc, e + 2), a3 = __shfl(msrc, e + 3);
                s0 += b2f(xin[(gn0 + a0) * DD + lane]);
                s1 += b2f(xin[(gn0 + a1) * DD + lane]);
                s2 += b2f(xin[(gn0 + a2) * DD + lane]);
                s3 += b2f(xin[(gn0 + a3) * DD + lane]);
            }
            if (e < nuse) {  // masked parallel tail (1..3), no serial chain
                int r = nuse - e;
                int a0 = __shfl(msrc, e);
                int a1 = __shfl(msrc, r > 1 ? e + 1 : e);
                int a2 = __shfl(msrc, r > 2 ? e + 2 : e);
                float v0 = b2f(xin[(gn0 + a0) * DD + lane]);
                float v1 = b2f(xin[(gn0 + a1) * DD + lane]);
                float v2 = b2f(xin[(gn0 + a2) * DD + lane]);
                s0 += v0;
                if (r > 1) s1 += v1;
                if (r > 2) s2 += v2;
            }
            mean = ((s0 + s1) + (s2 + s3)) / fmaxf((float)ne, 1.f);
        }
        sM[rl * DD + (lane ^ ((rl & 7) << 3))] = f2b(mean);  // own rows, 2-way free
    }

    // ---- MFMA phase (A-frags: direct b128 reads, conflict-free) ----
    int arow = w * 16 + (lane & 15);
    int kb = (lane >> 4) * 8;
    int selfrow = base + arow; if (selfrow > NN - 1) selfrow = NN - 1;  // clamp tail
    short8 am[2], ax[2];
#pragma unroll
    for (int ss = 0; ss < 2; ++ss) {
        int f0 = (kb + 32 * ss) ^ ((arow & 7) << 3);
        am[ss] = *(const short8*)&sM[arow * DD + f0];
        ax[ss] = *(const short8*)&xin[(gn0 + selfrow) * DD + kb + 32 * ss];
    }

    float4v acc[4];
#pragma unroll
    for (int c = 0; c < 4; ++c) {
        float b = bias[g * DD + c * 16 + (lane & 15)];
        acc[c] = {b, b, b, b};
    }
#pragma unroll
    for (int c = 0; c < 4; ++c) {
        int col = c * 16 + (lane & 15);
        int cswz = (col & 7) << 3;
#pragma unroll
        for (int ss = 0; ss < 2; ++ss) {
            short8 bl = *(const short8*)&sWT[0 * DD * DD + col * DD + ((kb + 32 * ss) ^ cswz)];
            acc[c] = __builtin_amdgcn_mfma_f32_16x16x32_bf16(am[ss], bl, acc[c], 0, 0, 0);
        }
#pragma unroll
        for (int ss = 0; ss < 2; ++ss) {
            short8 br = *(const short8*)&sWT[1 * DD * DD + col * DD + ((kb + 32 * ss) ^ cswz)];
            acc[c] = __builtin_amdgcn_mfma_f32_16x16x32_bf16(ax[ss], br, acc[c], 0, 0, 0);
        }
    }

    // ---- ELU + direct register->global store (4x 64B segments per store) ----
    int q = lane >> 4, cl = lane & 15;
#pragma unroll
    for (int c = 0; c < 4; ++c) {
        int col = c * 16 + cl;
#pragma unroll
        for (int r = 0; r < 4; ++r) {
            int grow = base + w * 16 + q * 4 + r;
            if (grow >= NN) continue;
            float v = acc[c][r];
            v = v > 0.f ? v : expm1f(v);
            if (LAYER == 0)
                ((unsigned short*)outp)[(gn0 + grow) * DD + col] = f2b(v);
            else
                ((float*)outp)[(gn0 + grow) * DD + col] = v;
        }
    }
}

// ---- fallback (proven shfl-matvec), grid-stride, runs only if probe failed --
template <int LAYER>
__global__ void fallback_kernel(const unsigned short* __restrict__ xin,
                                const int* __restrict__ cnt,
                                const unsigned short* __restrict__ bucket,
                                const float* __restrict__ Wl, const float* __restrict__ Wr,
                                const float* __restrict__ bias, void* __restrict__ outp,
                                const int* __restrict__ flags) {
    if (flags[0] & 2) return;
    __shared__ float sWl[DD * DD];
    __shared__ float sWr[DD * DD];
    __shared__ float sb[DD];
    int g = blockIdx.y;
    for (int i = threadIdx.x; i < DD * DD; i += blockDim.x) {
        sWl[i] = Wl[g * DD * DD + i];
        sWr[i] = Wr[g * DD * DD + i];
    }
    if (threadIdx.x < DD) sb[threadIdx.x] = bias[g * DD + threadIdx.x];
    __syncthreads();
    int lane = threadIdx.x & 63;
    int wpb = blockDim.x >> 6;
    long gn0 = (long)g * NN;
    for (int node = blockIdx.x * wpb + (threadIdx.x >> 6); node < NN;
         node += gridDim.x * wpb) {
        long row = gn0 + node;
        int ne = cnt[row];
        int nuse = ne < CAP ? ne : CAP;
        int msrc = (int)bucket[row * CAP + lane];
        float sum = 0.f;
        for (int e = 0; e < nuse; ++e) {
            int a0 = __shfl(msrc, e);
            sum += b2f(xin[(gn0 + a0) * DD + lane]);
        }
        float mean = sum / fmaxf((float)ne, 1.f);
        float self = b2f(xin[row * DD + lane]);
        float acc = sb[lane];
#pragma unroll
        for (int k = 0; k < DD; ++k) {
            float mk = __shfl(mean, k);
            float xk = __shfl(self, k);
            acc += mk * sWl[k * DD + lane] + xk * sWr[k * DD + lane];
        }
        acc = acc > 0.f ? acc : expm1f(acc);
        if (LAYER == 0) ((unsigned short*)outp)[row * DD + lane] = f2b(acc);
        else            ((float*)outp)[row * DD + lane] = acc;
    }
}

extern "C" void kernel_launch(void* const* d_in, const int* in_sizes, int n_in,
                              void* d_out, int out_size, void* d_ws, size_t ws_size,
                              hipStream_t stream) {
    const float* x   = (const float*)d_in[0];
    const int*   ei  = (const int*)d_in[1];
    const float* Wl1 = (const float*)d_in[2];
    const float* Wr1 = (const float*)d_in[3];
    const float* b1  = (const float*)d_in[4];
    const float* Wl2 = (const float*)d_in[5];
    const float* Wr2 = (const float*)d_in[6];
    const float* b2  = (const float*)d_in[7];
    float* out = (float*)d_out;

    // ws: cnt i32[200000] | bucket u16[200000*64] | h u16[200000*64] | flags i32
    // = 800000 + 25600000 + 25600000 + 4 = 52,000,004 B (proven budget)
    int* cnt = (int*)d_ws;
    unsigned short* bucket = (unsigned short*)(cnt + (size_t)NG * NN);
    unsigned short* h = bucket + (size_t)NG * NN * CAP;
    int* flags = (int*)(h + (size_t)NG * NN * DD);
    // xb (x as bf16, 25.6 MB) lives in d_out's first half; dead before layer 2
    unsigned short* xb = (unsigned short*)d_out;

    hipMemsetAsync(cnt, 0, (size_t)NG * NN * sizeof(int), stream);
    init_kernel<<<1, 64, 0, stream>>>(ei, flags);
    build_kernel<<<2048, 256, 0, stream>>>(ei, flags, cnt, bucket);
    convert_kernel<<<2048, 256, 0, stream>>>(x, xb);

    const int grid = NTILE * 8;  // 391 tb x 8 XCD slots
    dim3 fgrid(512, NG);
    // layer 1: xb -> h (bf16)
    sage_mfma_kernel<0><<<grid, 256, 0, stream>>>(xb, cnt, bucket, Wl1, Wr1, b1, h, flags);
    fallback_kernel<0><<<fgrid, 256, 0, stream>>>(xb, cnt, bucket, Wl1, Wr1, b1, h, flags);
    // layer 2: h -> out (f32)
    sage_mfma_kernel<1><<<grid, 256, 0, stream>>>(h, cnt, bucket, Wl2, Wr2, b2, out, flags);
    fallback_kernel<1><<<fgrid, 256, 0, stream>>>(h, cnt, bucket, Wl2, Wr2, b2, out, flags);
}

// Round 6
// 416.299 us; speedup vs baseline: 5.1122x; 1.0298x over previous
//
#include <hip/hip_runtime.h>
#include <hip/hip_bf16.h>
#include <math.h>

#define NG 4
#define NN 50000
#define NE 800000
#define DD 64
#define CAP 64
#define NT 64           // nodes per block tile
#define NTILE 391       // tiles per (graph, half): 391*64 = 25024 >= 25000

typedef __attribute__((ext_vector_type(8))) short short8;
typedef __attribute__((ext_vector_type(4))) float float4v;

__device__ __forceinline__ unsigned short f2b(float f) {
    union { __hip_bfloat16 h; unsigned short u; } cv;
    cv.h = __float2bfloat16(f);
    return cv.u;
}
__device__ __forceinline__ float b2f(unsigned short u) {
    union { unsigned short u; __hip_bfloat16 h; } cv;
    cv.u = u;
    return __bfloat162float(cv.h);
}

// ---- init: detect int64 (bit0) + verify MFMA layout (bit1), one block ------
__global__ void init_kernel(const int* __restrict__ ei, int* __restrict__ flags) {
    __shared__ alignas(16) unsigned short A[16 * 32];
    __shared__ unsigned short B[32 * 16];
    int t = threadIdx.x;
    int any_nonzero = 0;
    for (int i = t; i < 128; i += 64) any_nonzero |= ei[2 * i + 1];
    unsigned long long nz = __ballot(any_nonzero != 0);
    int is64 = (nz == 0ULL) ? 1 : 0;
    for (int i = t; i < 512; i += 64) {
        int r = i >> 5, k = i & 31;
        A[i] = f2b((float)(((r * 5 + k * 3) & 31) - 15));
        int kk = i >> 4, c = i & 15;
        B[i] = f2b((float)(((kk * 7 + c * 11) & 31) - 15));
    }
    __syncthreads();
    short8 a = *(const short8*)&A[(t & 15) * 32 + (t >> 4) * 8];
    int c = t & 15, kb = (t >> 4) * 8;
    short8 b;
    for (int j = 0; j < 8; ++j) b[j] = (short)B[(kb + j) * 16 + c];
    float4v acc = {0.f, 0.f, 0.f, 0.f};
    acc = __builtin_amdgcn_mfma_f32_16x16x32_bf16(a, b, acc, 0, 0, 0);
    int ok = 1;
    for (int reg = 0; reg < 4; ++reg) {
        int row = (t >> 4) * 4 + reg;
        float ref = 0.f;
        for (int k = 0; k < 32; ++k)
            ref += (float)(((row * 5 + k * 3) & 31) - 15) *
                   (float)(((k * 7 + c * 11) & 31) - 15);
        if (acc[reg] != ref) ok = 0;
    }
    unsigned long long vote = __ballot(ok);
    if (t == 0) flags[0] = is64 | ((vote == ~0ULL) ? 2 : 0);
}

// nt (streaming) edge-index load: keeps ei out of L2 so dirty bucket lines stay
__device__ __forceinline__ int nt_idx(const int* __restrict__ ei, long pos, int is64) {
    return is64 ? __builtin_nontemporal_load(ei + 2 * pos)
                : __builtin_nontemporal_load(ei + pos);
}
__device__ __forceinline__ int load_idx(const int* __restrict__ ei, long pos, int is64) {
    return is64 ? ei[2 * pos] : ei[pos];
}

// ---- bucket build, XCD-local + nt streaming + 8-wide ILP --------------------
// Slot s = blockIdx&7 -> XCD s (round-robin heuristic), graph s>>1, dst half
// s&1. Per-slot write footprint 3.3MB -> L2-resident; ei reads are nt so they
// don't evict dirty bucket lines. 8 edges/thread/iter: independent loads,
// atomics, stores (breaks the serial dst->src->atomic->store chain).
__global__ void build_kernel(const int* __restrict__ ei, const int* __restrict__ flags,
                             int* __restrict__ cnt, unsigned short* __restrict__ bucket) {
    const int CH = 8;
    int is64 = flags[0] & 1;
    int s = blockIdx.x & 7;
    int g = s >> 1;
    int lo = (s & 1) * (NN / 2), hi = lo + (NN / 2);
    int bsl = blockIdx.x >> 3;
    int nthreads = (gridDim.x >> 3) * blockDim.x;
    int tid = bsl * blockDim.x + threadIdx.x;
    long ebase = (long)g * 2 * NE;

    for (int e0 = tid; e0 < NE; e0 += nthreads * CH) {
        int dstv[CH], srcv[CH];
        bool ok[CH];
#pragma unroll
        for (int j = 0; j < CH; ++j) {
            int e = e0 + j * nthreads;
            bool inb = e < NE;
            int ec = inb ? e : NE - 1;            // clamped: always-valid address
            int d = nt_idx(ei, ebase + NE + ec, is64);
            dstv[j] = d;
            ok[j] = inb && d >= lo && d < hi;
        }
#pragma unroll
        for (int j = 0; j < CH; ++j) {
            int e = e0 + j * nthreads;
            int ec = e < NE ? e : NE - 1;
            srcv[j] = nt_idx(ei, ebase + ec, is64);  // unconditional (no branch)
        }
        int posv[CH];
#pragma unroll
        for (int j = 0; j < CH; ++j)
            posv[j] = ok[j] ? atomicAdd(&cnt[g * NN + dstv[j]], 1) : CAP;
#pragma unroll
        for (int j = 0; j < CH; ++j)
            if (posv[j] < CAP)
                bucket[(long)(g * NN + dstv[j]) * CAP + posv[j]] = (unsigned short)srcv[j];
    }
}

// ---- convert x f32 -> bf16 -------------------------------------------------
__global__ void convert_kernel(const float* __restrict__ x, unsigned short* __restrict__ xb) {
    long total = (long)NG * NN * DD / 4;
    long stride = (long)gridDim.x * blockDim.x;
    const float4* src = (const float4*)x;
    unsigned long long* dst = (unsigned long long*)xb;
    for (long i = (long)blockIdx.x * blockDim.x + threadIdx.x; i < total; i += stride) {
        float4 v = src[i];
        unsigned long long p = (unsigned long long)f2b(v.x)
                             | ((unsigned long long)f2b(v.y) << 16)
                             | ((unsigned long long)f2b(v.z) << 32)
                             | ((unsigned long long)f2b(v.w) << 48);
        dst[i] = p;
    }
}

// ---- fused gather + MFMA layer (unchanged from round 5) ---------------------
template <int LAYER>  // 0: out = h (bf16), 1: out = d_out (f32)
__launch_bounds__(256, 6)
__global__ void sage_mfma_kernel(const unsigned short* __restrict__ xin,
                                 const int* __restrict__ cnt,
                                 const unsigned short* __restrict__ bucket,
                                 const float* __restrict__ Wl, const float* __restrict__ Wr,
                                 const float* __restrict__ bias, void* __restrict__ outp,
                                 const int* __restrict__ flags) {
    if (!(flags[0] & 2)) return;
    __shared__ alignas(16) unsigned short sWT[2 * DD * DD];  // [m][col][k^swz] bf16, 16KB
    __shared__ alignas(16) unsigned short sM[NT * DD];       // [row][lane^swz] bf16, 8KB

    int s = blockIdx.x & 7, tb = blockIdx.x >> 3;
    int g = s >> 1;
    int tile = (s & 1) * NTILE + tb;      // halves match build partition
    int base = tile * NT;
    long gn0 = (long)g * NN;

    for (int i = threadIdx.x; i < 1024; i += 256) {
        int col = i & 63, ko = (i >> 6) & 7, m = i >> 9;
        const float* Wsrc = (m == 0 ? Wl : Wr) + (long)g * DD * DD;
        short8 t;
#pragma unroll
        for (int j = 0; j < 8; ++j)
            t[j] = (short)f2b(Wsrc[(ko * 8 + j) * DD + col]);
        *(short8*)&sWT[m * DD * DD + col * DD + ((ko * 8) ^ ((col & 7) << 3))] = t;
    }
    __syncthreads();

    int lane = threadIdx.x & 63;
    int w = threadIdx.x >> 6;

#pragma unroll 1
    for (int j = 0; j < 16; ++j) {
        int rl = w * 16 + j;
        int node = base + rl;
        float mean = 0.f;
        if (node < NN) {
            long row = gn0 + node;
            int ne = cnt[row];
            int nuse = ne < CAP ? ne : CAP;
            int msrc = (int)bucket[row * CAP + lane];
            float s0 = 0.f, s1 = 0.f, s2 = 0.f, s3 = 0.f;
            int e = 0;
            for (; e + 4 <= nuse; e += 4) {
                int a0 = __shfl(msrc, e), a1 = __shfl(msrc, e + 1);
                int a2 = __shfl(msrc, e + 2), a3 = __shfl(msrc, e + 3);
                s0 += b2f(xin[(gn0 + a0) * DD + lane]);
                s1 += b2f(xin[(gn0 + a1) * DD + lane]);
                s2 += b2f(xin[(gn0 + a2) * DD + lane]);
                s3 += b2f(xin[(gn0 + a3) * DD + lane]);
            }
            if (e < nuse) {
                int r = nuse - e;
                int a0 = __shfl(msrc, e);
                int a1 = __shfl(msrc, r > 1 ? e + 1 : e);
                int a2 = __shfl(msrc, r > 2 ? e + 2 : e);
                float v0 = b2f(xin[(gn0 + a0) * DD + lane]);
                float v1 = b2f(xin[(gn0 + a1) * DD + lane]);
                float v2 = b2f(xin[(gn0 + a2) * DD + lane]);
                s0 += v0;
                if (r > 1) s1 += v1;
                if (r > 2) s2 += v2;
            }
            mean = ((s0 + s1) + (s2 + s3)) / fmaxf((float)ne, 1.f);
        }
        sM[rl * DD + (lane ^ ((rl & 7) << 3))] = f2b(mean);
    }

    int arow = w * 16 + (lane & 15);
    int kb = (lane >> 4) * 8;
    int selfrow = base + arow; if (selfrow > NN - 1) selfrow = NN - 1;
    short8 am[2], ax[2];
#pragma unroll
    for (int ss = 0; ss < 2; ++ss) {
        int f0 = (kb + 32 * ss) ^ ((arow & 7) << 3);
        am[ss] = *(const short8*)&sM[arow * DD + f0];
        ax[ss] = *(const short8*)&xin[(gn0 + selfrow) * DD + kb + 32 * ss];
    }

    float4v acc[4];
#pragma unroll
    for (int c = 0; c < 4; ++c) {
        float b = bias[g * DD + c * 16 + (lane & 15)];
        acc[c] = {b, b, b, b};
    }
#pragma unroll
    for (int c = 0; c < 4; ++c) {
        int col = c * 16 + (lane & 15);
        int cswz = (col & 7) << 3;
#pragma unroll
        for (int ss = 0; ss < 2; ++ss) {
            short8 bl = *(const short8*)&sWT[0 * DD * DD + col * DD + ((kb + 32 * ss) ^ cswz)];
            acc[c] = __builtin_amdgcn_mfma_f32_16x16x32_bf16(am[ss], bl, acc[c], 0, 0, 0);
        }
#pragma unroll
        for (int ss = 0; ss < 2; ++ss) {
            short8 br = *(const short8*)&sWT[1 * DD * DD + col * DD + ((kb + 32 * ss) ^ cswz)];
            acc[c] = __builtin_amdgcn_mfma_f32_16x16x32_bf16(ax[ss], br, acc[c], 0, 0, 0);
        }
    }

    int q = lane >> 4, cl = lane & 15;
#pragma unroll
    for (int c = 0; c < 4; ++c) {
        int col = c * 16 + cl;
#pragma unroll
        for (int r = 0; r < 4; ++r) {
            int grow = base + w * 16 + q * 4 + r;
            if (grow >= NN) continue;
            float v = acc[c][r];
            v = v > 0.f ? v : expm1f(v);
            if (LAYER == 0)
                ((unsigned short*)outp)[(gn0 + grow) * DD + col] = f2b(v);
            else
                ((float*)outp)[(gn0 + grow) * DD + col] = v;
        }
    }
}

// ---- fallback (proven shfl-matvec), runs only if probe failed ---------------
template <int LAYER>
__global__ void fallback_kernel(const unsigned short* __restrict__ xin,
                                const int* __restrict__ cnt,
                                const unsigned short* __restrict__ bucket,
                                const float* __restrict__ Wl, const float* __restrict__ Wr,
                                const float* __restrict__ bias, void* __restrict__ outp,
                                const int* __restrict__ flags) {
    if (flags[0] & 2) return;
    __shared__ float sWl[DD * DD];
    __shared__ float sWr[DD * DD];
    __shared__ float sb[DD];
    int g = blockIdx.y;
    for (int i = threadIdx.x; i < DD * DD; i += blockDim.x) {
        sWl[i] = Wl[g * DD * DD + i];
        sWr[i] = Wr[g * DD * DD + i];
    }
    if (threadIdx.x < DD) sb[threadIdx.x] = bias[g * DD + threadIdx.x];
    __syncthreads();
    int lane = threadIdx.x & 63;
    int wpb = blockDim.x >> 6;
    long gn0 = (long)g * NN;
    for (int node = blockIdx.x * wpb + (threadIdx.x >> 6); node < NN;
         node += gridDim.x * wpb) {
        long row = gn0 + node;
        int ne = cnt[row];
        int nuse = ne < CAP ? ne : CAP;
        int msrc = (int)bucket[row * CAP + lane];
        float sum = 0.f;
        for (int e = 0; e < nuse; ++e) {
            int a0 = __shfl(msrc, e);
            sum += b2f(xin[(gn0 + a0) * DD + lane]);
        }
        float mean = sum / fmaxf((float)ne, 1.f);
        float self = b2f(xin[row * DD + lane]);
        float acc = sb[lane];
#pragma unroll
        for (int k = 0; k < DD; ++k) {
            float mk = __shfl(mean, k);
            float xk = __shfl(self, k);
            acc += mk * sWl[k * DD + lane] + xk * sWr[k * DD + lane];
        }
        acc = acc > 0.f ? acc : expm1f(acc);
        if (LAYER == 0) ((unsigned short*)outp)[row * DD + lane] = f2b(acc);
        else            ((float*)outp)[row * DD + lane] = acc;
    }
}

extern "C" void kernel_launch(void* const* d_in, const int* in_sizes, int n_in,
                              void* d_out, int out_size, void* d_ws, size_t ws_size,
                              hipStream_t stream) {
    const float* x   = (const float*)d_in[0];
    const int*   ei  = (const int*)d_in[1];
    const float* Wl1 = (const float*)d_in[2];
    const float* Wr1 = (const float*)d_in[3];
    const float* b1  = (const float*)d_in[4];
    const float* Wl2 = (const float*)d_in[5];
    const float* Wr2 = (const float*)d_in[6];
    const float* b2  = (const float*)d_in[7];
    float* out = (float*)d_out;

    // ws: cnt i32[200000] | bucket u16[200000*64] | h u16[200000*64] | flags i32
    // = 800000 + 25600000 + 25600000 + 4 = 52,000,004 B (proven budget)
    int* cnt = (int*)d_ws;
    unsigned short* bucket = (unsigned short*)(cnt + (size_t)NG * NN);
    unsigned short* h = bucket + (size_t)NG * NN * CAP;
    int* flags = (int*)(h + (size_t)NG * NN * DD);
    // xb (x as bf16, 25.6 MB) lives in d_out's first half; dead before layer 2
    unsigned short* xb = (unsigned short*)d_out;

    hipMemsetAsync(cnt, 0, (size_t)NG * NN * sizeof(int), stream);
    init_kernel<<<1, 64, 0, stream>>>(ei, flags);
    build_kernel<<<2048, 256, 0, stream>>>(ei, flags, cnt, bucket);
    convert_kernel<<<2048, 256, 0, stream>>>(x, xb);

    const int grid = NTILE * 8;  // 391 tb x 8 XCD slots
    dim3 fgrid(512, NG);
    // layer 1: xb -> h (bf16)
    sage_mfma_kernel<0><<<grid, 256, 0, stream>>>(xb, cnt, bucket, Wl1, Wr1, b1, h, flags);
    fallback_kernel<0><<<fgrid, 256, 0, stream>>>(xb, cnt, bucket, Wl1, Wr1, b1, h, flags);
    // layer 2: h -> out (f32)
    sage_mfma_kernel<1><<<grid, 256, 0, stream>>>(h, cnt, bucket, Wl2, Wr2, b2, out, flags);
    fallback_kernel<1><<<fgrid, 256, 0, stream>>>(h, cnt, bucket, Wl2, Wr2, b2, out, flags);
}